// Round 3
// baseline (376.642 us; speedup 1.0000x reference)
//
#include <hip/hip_runtime.h>
#include <hip/hip_bf16.h>

// clip_nce: Q=16384 queries, V=4096 videos, scores [Q,V] fp32, labels [Q] int.
// Single-pass streaming: row logsumexp + column exp-sums in one read of the
// 256 MiB matrix. ~half the matrix is L3-resident (harness restore copy), so
// effective ceiling is above HBM 6.3 TB/s.
// R2 -> R3 (latency/MLP attack):
//  - 256-thread blocks x 1024 (finer residency granules, more blocks/CU)
//  - explicit software pipeline: chunk c+1's 4 loads issued before chunk c's
//    compute -> each wave keeps ~4 KB in flight continuously
//  - column partials via transposed-LDS ds-atomics (bank = lane%32, 2-way = free)

#define QN 16384
#define VN 4096
#define NBLK 1024   // main_pass blocks (4 waves each, 4 rows per wave)

// workspace layout in floats (~17 MiB):
#define COLPART_OFF 0                        // NBLK * 4096 block column partials
#define T2V_OFF     (NBLK * VN)              // 16384: log(rowsum_q) - s_q
#define NOMSUM_OFF  (T2V_OFF + QN)           // 4096: sum exp(s) per label
#define COLSUM_OFF  (NOMSUM_OFF + VN)        // 4096: column exp-sums (permuted)
#define ACC_OFF     (COLSUM_OFF + VN)        // scalars

__global__ __launch_bounds__(512) void init_pass(float* __restrict__ ws) {
    int i = blockIdx.x * 512 + threadIdx.x;
    int n = VN + VN + 8;   // nomsum + colsum + accumulators
    if (i < n) ws[NOMSUM_OFF + i] = 0.0f;
}

// 1024 blocks x 256 threads (4 waves); each wave owns 4 full rows.
__global__ __launch_bounds__(256, 4) void main_pass(const float* __restrict__ scores,
                                                    const int* __restrict__ labels,
                                                    float* __restrict__ ws) {
    float* colPartial = ws + COLPART_OFF;
    float* t2v        = ws + T2V_OFF;
    float* nomsum     = ws + NOMSUM_OFF;

    // transposed layout: element (idx, comp) of the float4 stream -> comp*1024 + idx
    __shared__ __align__(16) float lcolT[VN];
    const int tid  = threadIdx.x;
    const int wid  = tid >> 6;
    const int lane = tid & 63;

    for (int i = tid; i < VN; i += 256) lcolT[i] = 0.0f;
    __syncthreads();

    const int gw   = blockIdx.x * 4 + wid;   // global wave id, 4096 waves
    const int row0 = gw * 4;
    const float4* p0 = reinterpret_cast<const float4*>(scores + (size_t)row0 * VN);
    const float4* p1 = p0 + 1024;
    const float4* p2 = p0 + 2048;
    const float4* p3 = p0 + 3072;

    float ra0 = 0.f, ra1 = 0.f, ra2 = 0.f, ra3 = 0.f;

    // software pipeline: xa* = current chunk's data, xb* = next chunk in flight
    float4 xa0 = p0[lane];
    float4 xa1 = p1[lane];
    float4 xa2 = p2[lane];
    float4 xa3 = p3[lane];

#pragma unroll
    for (int c = 0; c < 16; ++c) {
        float4 xb0, xb1, xb2, xb3;
        if (c < 15) {
            const int nidx = (c + 1) * 64 + lane;
            xb0 = p0[nidx];                  // next chunk: 4 KB/wave in flight
            xb1 = p1[nidx];
            xb2 = p2[nidx];
            xb3 = p3[nidx];
        } else {
            xb0 = xa0; xb1 = xa1; xb2 = xa2; xb3 = xa3;  // dead after unroll
        }

        const int idx = c * 64 + lane;
        float4 e0, e1, e2, e3;
        e0.x = __expf(xa0.x); e0.y = __expf(xa0.y); e0.z = __expf(xa0.z); e0.w = __expf(xa0.w);
        e1.x = __expf(xa1.x); e1.y = __expf(xa1.y); e1.z = __expf(xa1.z); e1.w = __expf(xa1.w);
        e2.x = __expf(xa2.x); e2.y = __expf(xa2.y); e2.z = __expf(xa2.z); e2.w = __expf(xa2.w);
        e3.x = __expf(xa3.x); e3.y = __expf(xa3.y); e3.z = __expf(xa3.z); e3.w = __expf(xa3.w);
        ra0 += (e0.x + e0.y) + (e0.z + e0.w);
        ra1 += (e1.x + e1.y) + (e1.z + e1.w);
        ra2 += (e2.x + e2.y) + (e2.z + e2.w);
        ra3 += (e3.x + e3.y) + (e3.z + e3.w);
        // column partials -> transposed LDS; bank = lane%32 (2-way, free)
        atomicAdd(&lcolT[0 * 1024 + idx], (e0.x + e1.x) + (e2.x + e3.x));
        atomicAdd(&lcolT[1 * 1024 + idx], (e0.y + e1.y) + (e2.y + e3.y));
        atomicAdd(&lcolT[2 * 1024 + idx], (e0.z + e1.z) + (e2.z + e3.z));
        atomicAdd(&lcolT[3 * 1024 + idx], (e0.w + e1.w) + (e2.w + e3.w));

        xa0 = xb0; xa1 = xb1; xa2 = xb2; xa3 = xb3;
    }

    // once-per-wave tail: 4 interleaved butterfly reductions for the row sums
#pragma unroll
    for (int off = 32; off >= 1; off >>= 1) {
        ra0 += __shfl_down(ra0, off);
        ra1 += __shfl_down(ra1, off);
        ra2 += __shfl_down(ra2, off);
        ra3 += __shfl_down(ra3, off);
    }

    // label gather: lanes 0..3 handle rows row0..row0+3
    float s_val = 0.f;
    if (lane < 4) {
        const int lab = labels[row0 + lane];
        s_val = scores[(size_t)(row0 + lane) * VN + lab];
        unsafeAtomicAdd(&nomsum[lab], __expf(s_val));
    }
    const float s0 = __shfl(s_val, 0);
    const float s1 = __shfl(s_val, 1);
    const float s2 = __shfl(s_val, 2);
    const float s3 = __shfl(s_val, 3);
    if (lane == 0) {
        t2v[row0 + 0] = __logf(ra0) - s0;
        t2v[row0 + 1] = __logf(ra1) - s1;
        t2v[row0 + 2] = __logf(ra2) - s2;
        t2v[row0 + 3] = __logf(ra3) - s3;
    }

    __syncthreads();
    float4* dst = reinterpret_cast<float4*>(colPartial + (size_t)blockIdx.x * VN);
    const float4* src = reinterpret_cast<const float4*>(lcolT);
    dst[tid]       = src[tid];
    dst[tid + 256] = src[tid + 256];
    dst[tid + 512] = src[tid + 512];
    dst[tid + 768] = src[tid + 768];
}

// blocks 0..255: reduce NBLK column partials -> atomic into colsum
//   (cg = col group of 256, bg = 16 groups of NBLK/16 partial rows)
// blocks 256..319: reduce t2v[16384] -> atomic scalar
__global__ __launch_bounds__(256) void reduce_pass(float* __restrict__ ws) {
    const float* colPartial = ws + COLPART_OFF;
    const float* t2v        = ws + T2V_OFF;
    float* colsum = ws + COLSUM_OFF;
    float* acc    = ws + ACC_OFF;
    const int tid = threadIdx.x;

    if (blockIdx.x < 256) {
        const int cg  = blockIdx.x & 15;
        const int bg  = blockIdx.x >> 4;
        const int col = cg * 256 + tid;
        const int per = NBLK / 16;
        float sum = 0.0f;
#pragma unroll 4
        for (int b = bg * per; b < bg * per + per; ++b)
            sum += colPartial[(size_t)b * VN + col];
        unsafeAtomicAdd(&colsum[col], sum);
    } else {
        const int idx = (blockIdx.x - 256) * 256 + tid;
        float v = t2v[idx];
#pragma unroll
        for (int off = 32; off >= 1; off >>= 1)
            v += __shfl_down(v, off);
        __shared__ float red[4];
        const int wid = tid >> 6, lane = tid & 63;
        if (lane == 0) red[wid] = v;
        __syncthreads();
        if (tid == 0)
            unsafeAtomicAdd(&acc[0], (red[0] + red[1]) + (red[2] + red[3]));
    }
}

__global__ __launch_bounds__(256) void final_pass(const float* __restrict__ ws,
                                                  float* __restrict__ out) {
    const float* nomsum = ws + NOMSUM_OFF;
    const float* colsum = ws + COLSUM_OFF;
    const float* acc    = ws + ACC_OFF;
    const int tid = threadIdx.x;

    // sum(log colsum) is order-independent -> permuted colsum is fine
    float local = 0.0f;
    for (int c = tid; c < VN; c += 256)
        local += __logf(colsum[c]) - __logf(nomsum[c]);
#pragma unroll
    for (int off = 32; off >= 1; off >>= 1)
        local += __shfl_down(local, off);
    __shared__ float red[4];
    const int wid = tid >> 6, lane = tid & 63;
    if (lane == 0) red[wid] = local;
    __syncthreads();
    if (tid == 0) {
        const float v2t = (red[0] + red[1]) + (red[2] + red[3]);
        out[0] = acc[0] * (1.0f / QN) + v2t * (1.0f / VN);
    }
}

extern "C" void kernel_launch(void* const* d_in, const int* in_sizes, int n_in,
                              void* d_out, int out_size, void* d_ws, size_t ws_size,
                              hipStream_t stream) {
    const float* scores = (const float*)d_in[0];
    const int*   labels = (const int*)d_in[1];
    float* ws  = (float*)d_ws;
    float* out = (float*)d_out;

    init_pass<<<(2 * VN + 8 + 511) / 512, 512, 0, stream>>>(ws);
    main_pass<<<NBLK, 256, 0, stream>>>(scores, labels, ws);
    reduce_pass<<<320, 256, 0, stream>>>(ws);
    final_pass<<<1, 256, 0, stream>>>(ws, out);
}

// Round 4
// 375.962 us; speedup vs baseline: 1.0018x; 1.0018x over previous
//
#include <hip/hip_runtime.h>
#include <hip/hip_bf16.h>

// clip_nce: Q=16384 queries, V=4096 videos, scores [Q,V] fp32, labels [Q] int.
// One read of the 256 MiB matrix computing row logsumexp + column exp-sums.
// R3 -> R4: main_pass restructured to a GRID-STRIDE CONTIGUOUS SWEEP
// (isomorphic to the 6.29 TB/s m13 copy pattern): at every instant the whole
// grid reads one dense 8 MB window, instead of 4096 dispersed power-of-2-
// strided streams. Per block-iteration all threads hit ONE row (row sums via
// shuffle + 1 global fp atomic per wave-iter); each thread owns a FIXED set
// of 4 columns (register-only column accumulation, no LDS in the loop).

#define QN 16384
#define VN 4096
#define NB 2048
#define TB 256
#define STEP (NB * TB)                    // float4s per sweep step = 524288 (8 MB)
#define ITERS ((QN * (VN / 4)) / STEP)    // 32
#define ROWS_PER_STEP (STEP / (VN / 4))   // 512

// workspace layout in floats (~8.4 MiB):
#define COLCOMP_OFF 0                     // NB*1024 compact column partials
#define ROWSUM_OFF  (NB * 1024)           // QN: sum exp per row (global atomics)
#define NOMSUM_OFF  (ROWSUM_OFF + QN)     // VN: sum exp(s) per label
#define COLSUM_OFF  (NOMSUM_OFF + VN)     // VN: column exp-sums (natural order)
#define ACC_OFF     (COLSUM_OFF + VN)     // [0]=sum log rowsum, [1]=sum s

__global__ __launch_bounds__(256) void init_pass(float* __restrict__ ws) {
    int i = blockIdx.x * 256 + threadIdx.x;
    int n = QN + VN + VN + 8;   // rowsum + nomsum + colsum + acc
    if (i < n) ws[ROWSUM_OFF + i] = 0.0f;
}

// Grid-stride dense sweep. Thread (b,t): float4 index k*STEP + b*256 + t.
//  row = k*ROWS_PER_STEP + (b>>2)  (whole block in one row per iteration)
//  columns = (b&3)*1024 + t*4 + {0..3}  (fixed for all k -> register colacc)
__global__ __launch_bounds__(256) void main_pass(const float* __restrict__ scores,
                                                 float* __restrict__ ws) {
    float* rowsum  = ws + ROWSUM_OFF;
    float* colcomp = ws + COLCOMP_OFF;
    const int tid  = threadIdx.x;
    const int b    = blockIdx.x;
    const int lane = tid & 63;
    const float4* sp = reinterpret_cast<const float4*>(scores);
    const int base = b * TB + tid;
    const int rowInStep = base >> 10;      // == b>>2, constant per block

    float c0 = 0.f, c1 = 0.f, c2 = 0.f, c3 = 0.f;

#pragma unroll 8
    for (int k = 0; k < ITERS; ++k) {
        float4 x = sp[(size_t)k * STEP + base];   // dense 8 MB window per k
        float e0 = __expf(x.x), e1 = __expf(x.y);
        float e2 = __expf(x.z), e3 = __expf(x.w);
        c0 += e0; c1 += e1; c2 += e2; c3 += e3;
        float rp = (e0 + e1) + (e2 + e3);
#pragma unroll
        for (int off = 32; off >= 1; off >>= 1)
            rp += __shfl_down(rp, off);
        if (lane == 0)   // 16 atomics per row address total across the grid
            unsafeAtomicAdd(&rowsum[k * ROWS_PER_STEP + rowInStep], rp);
    }

    // compact col partials: colcomp[b*1024 + t*4 + j] <-> col (b&3)*1024 + t*4 + j
    float4 o; o.x = c0; o.y = c1; o.z = c2; o.w = c3;
    reinterpret_cast<float4*>(colcomp)[b * TB + tid] = o;
}

// 16384 label gathers (one cache line each, fully parallel) + nomsum + sum(s)
__global__ __launch_bounds__(256) void gather_pass(const float* __restrict__ scores,
                                                   const int* __restrict__ labels,
                                                   float* __restrict__ ws) {
    float* nomsum = ws + NOMSUM_OFF;
    float* acc    = ws + ACC_OFF;
    const int i = blockIdx.x * 256 + threadIdx.x;
    const int lab = labels[i];
    const float s = scores[(size_t)i * VN + lab];
    unsafeAtomicAdd(&nomsum[lab], __expf(s));
    float v = s;
#pragma unroll
    for (int off = 32; off >= 1; off >>= 1)
        v += __shfl_down(v, off);
    if ((threadIdx.x & 63) == 0) unsafeAtomicAdd(&acc[1], v);
}

// blocks [0,128): colsum from compact partials (8 MiB read).
//   block = q*32 + cc*8 + mg: quarter q, col-chunk cc, m-range mg (64 blocks each)
// blocks [128,192): sum log rowsum -> acc[0]
__global__ __launch_bounds__(256) void reduce_pass(float* __restrict__ ws) {
    const float* colcomp = ws + COLCOMP_OFF;
    const float* rowsum  = ws + ROWSUM_OFF;
    float* colsum = ws + COLSUM_OFF;
    float* acc    = ws + ACC_OFF;
    const int tid = threadIdx.x;

    if (blockIdx.x < 128) {
        const int q  = blockIdx.x >> 5;          // column quarter 0..3
        const int cc = (blockIdx.x >> 3) & 3;    // 256-col chunk 0..3
        const int mg = blockIdx.x & 7;           // m-range 0..7
        const int c  = cc * 256 + tid;           // col within quarter [0,1024)
        float sum = 0.0f;
#pragma unroll 4
        for (int m = mg * 64; m < mg * 64 + 64; ++m)
            sum += colcomp[(size_t)(4 * m + q) * 1024 + c];
        unsafeAtomicAdd(&colsum[q * 1024 + c], sum);
    } else {
        const int idx = (blockIdx.x - 128) * 256 + tid;
        float v = __logf(rowsum[idx]);
#pragma unroll
        for (int off = 32; off >= 1; off >>= 1)
            v += __shfl_down(v, off);
        if ((tid & 63) == 0) unsafeAtomicAdd(&acc[0], v);
    }
}

__global__ __launch_bounds__(256) void final_pass(const float* __restrict__ ws,
                                                  float* __restrict__ out) {
    const float* nomsum = ws + NOMSUM_OFF;
    const float* colsum = ws + COLSUM_OFF;
    const float* acc    = ws + ACC_OFF;
    const int tid = threadIdx.x;

    float local = 0.0f;
    for (int c = tid; c < VN; c += 256)
        local += __logf(colsum[c]) - __logf(nomsum[c]);
#pragma unroll
    for (int off = 32; off >= 1; off >>= 1)
        local += __shfl_down(local, off);
    __shared__ float red[4];
    const int wid = tid >> 6, lane = tid & 63;
    if (lane == 0) red[wid] = local;
    __syncthreads();
    if (tid == 0) {
        const float v2t = (red[0] + red[1]) + (red[2] + red[3]);
        // mean(log rowsum - s) + mean(log colsum - log nomsum)
        out[0] = (acc[0] - acc[1]) * (1.0f / QN) + v2t * (1.0f / VN);
    }
}

extern "C" void kernel_launch(void* const* d_in, const int* in_sizes, int n_in,
                              void* d_out, int out_size, void* d_ws, size_t ws_size,
                              hipStream_t stream) {
    const float* scores = (const float*)d_in[0];
    const int*   labels = (const int*)d_in[1];
    float* ws  = (float*)d_ws;
    float* out = (float*)d_out;

    init_pass<<<(QN + VN + VN + 8 + 255) / 256, 256, 0, stream>>>(ws);
    main_pass<<<NB, TB, 0, stream>>>(scores, ws);
    gather_pass<<<QN / 256, 256, 0, stream>>>(scores, labels, ws);
    reduce_pass<<<192, 256, 0, stream>>>(ws);
    final_pass<<<1, 256, 0, stream>>>(ws, out);
}

// Round 5
// 363.658 us; speedup vs baseline: 1.0357x; 1.0338x over previous
//
#include <hip/hip_runtime.h>
#include <hip/hip_bf16.h>

// clip_nce: Q=16384 queries, V=4096 videos, scores [Q,V] fp32, labels [Q] int.
// One read of the 256 MiB matrix computing row logsumexp + column exp-sums.
// R4 -> R5: NON-TEMPORAL loads for the score stream. Evidence: three
// structurally different main_pass versions all hit exactly ~2.4 TB/s read;
// harness fill (pure writes) hits 6.7 TB/s; m13 copy = 3.15 TB/s read-side.
// => per-CU L1 read-allocation path is the cap. nt loads bypass L1.

#define QN 16384
#define VN 4096
#define NB 2048
#define TB 256
#define STEP (NB * TB)                    // float4s per sweep step = 524288 (8 MB)
#define ITERS ((QN * (VN / 4)) / STEP)    // 32
#define ROWS_PER_STEP (STEP / (VN / 4))   // 512

typedef float f32x4 __attribute__((ext_vector_type(4)));

// workspace layout in floats (~8.4 MiB):
#define COLCOMP_OFF 0                     // NB*1024 compact column partials
#define ROWSUM_OFF  (NB * 1024)           // QN: sum exp per row (global atomics)
#define NOMSUM_OFF  (ROWSUM_OFF + QN)     // VN: sum exp(s) per label
#define COLSUM_OFF  (NOMSUM_OFF + VN)     // VN: column exp-sums (natural order)
#define ACC_OFF     (COLSUM_OFF + VN)     // [0]=sum log rowsum, [1]=sum s

__global__ __launch_bounds__(256) void init_pass(float* __restrict__ ws) {
    int i = blockIdx.x * 256 + threadIdx.x;
    int n = QN + VN + VN + 8;   // rowsum + nomsum + colsum + acc
    if (i < n) ws[ROWSUM_OFF + i] = 0.0f;
}

// 16384 label gathers (one cache line each) + nomsum + sum(s)
__global__ __launch_bounds__(256) void gather_pass(const float* __restrict__ scores,
                                                   const int* __restrict__ labels,
                                                   float* __restrict__ ws) {
    float* nomsum = ws + NOMSUM_OFF;
    float* acc    = ws + ACC_OFF;
    const int i = blockIdx.x * 256 + threadIdx.x;
    const int lab = labels[i];
    const float s = scores[(size_t)i * VN + lab];
    unsafeAtomicAdd(&nomsum[lab], __expf(s));
    float v = s;
#pragma unroll
    for (int off = 32; off >= 1; off >>= 1)
        v += __shfl_down(v, off);
    if ((threadIdx.x & 63) == 0) unsafeAtomicAdd(&acc[1], v);
}

// Grid-stride dense sweep with NON-TEMPORAL reads.
// Thread (b,t): float4 index k*STEP + b*256 + t.
//  row = k*ROWS_PER_STEP + (b>>2)  (whole block in one row per iteration)
//  columns = (b&3)*1024 + t*4 + {0..3}  (fixed for all k -> register colacc)
__global__ __launch_bounds__(256, 8) void main_pass(const float* __restrict__ scores,
                                                    float* __restrict__ ws) {
    float* rowsum  = ws + ROWSUM_OFF;
    float* colcomp = ws + COLCOMP_OFF;
    const int tid  = threadIdx.x;
    const int b    = blockIdx.x;
    const int lane = tid & 63;
    const f32x4* sp = reinterpret_cast<const f32x4*>(scores);
    const int base = b * TB + tid;
    const int rowInStep = base >> 10;      // == b>>2, constant per block

    float c0 = 0.f, c1 = 0.f, c2 = 0.f, c3 = 0.f;

#pragma unroll 8
    for (int k = 0; k < ITERS; ++k) {
        f32x4 x = __builtin_nontemporal_load(&sp[(size_t)k * STEP + base]);
        float e0 = __expf(x.x), e1 = __expf(x.y);
        float e2 = __expf(x.z), e3 = __expf(x.w);
        c0 += e0; c1 += e1; c2 += e2; c3 += e3;
        float rp = (e0 + e1) + (e2 + e3);
#pragma unroll
        for (int off = 32; off >= 1; off >>= 1)
            rp += __shfl_down(rp, off);
        if (lane == 0)   // 16 atomics per row address total across the grid
            unsafeAtomicAdd(&rowsum[k * ROWS_PER_STEP + rowInStep], rp);
    }

    // compact col partials: colcomp[b*256*4 + t*4 + j] <-> col (b&3)*1024 + t*4 + j
    f32x4 o; o.x = c0; o.y = c1; o.z = c2; o.w = c3;
    reinterpret_cast<f32x4*>(colcomp)[b * TB + tid] = o;
}

// blocks [0,128): colsum from compact partials (8 MiB read).
//   block = q*32 + cc*8 + mg: quarter q, col-chunk cc, m-range mg
// blocks [128,192): sum log rowsum -> acc[0]
__global__ __launch_bounds__(256) void reduce_pass(float* __restrict__ ws) {
    const float* colcomp = ws + COLCOMP_OFF;
    const float* rowsum  = ws + ROWSUM_OFF;
    float* colsum = ws + COLSUM_OFF;
    float* acc    = ws + ACC_OFF;
    const int tid = threadIdx.x;

    if (blockIdx.x < 128) {
        const int q  = blockIdx.x >> 5;          // column quarter 0..3
        const int cc = (blockIdx.x >> 3) & 3;    // 256-col chunk 0..3
        const int mg = blockIdx.x & 7;           // m-range 0..7
        const int c  = cc * 256 + tid;           // col within quarter [0,1024)
        float sum = 0.0f;
#pragma unroll 4
        for (int m = mg * 64; m < mg * 64 + 64; ++m)
            sum += colcomp[(size_t)(4 * m + q) * 1024 + c];
        unsafeAtomicAdd(&colsum[q * 1024 + c], sum);
    } else {
        const int idx = (blockIdx.x - 128) * 256 + tid;
        float v = __logf(rowsum[idx]);
#pragma unroll
        for (int off = 32; off >= 1; off >>= 1)
            v += __shfl_down(v, off);
        if ((tid & 63) == 0) unsafeAtomicAdd(&acc[0], v);
    }
}

__global__ __launch_bounds__(256) void final_pass(const float* __restrict__ ws,
                                                  float* __restrict__ out) {
    const float* nomsum = ws + NOMSUM_OFF;
    const float* colsum = ws + COLSUM_OFF;
    const float* acc    = ws + ACC_OFF;
    const int tid = threadIdx.x;

    float local = 0.0f;
    for (int c = tid; c < VN; c += 256)
        local += __logf(colsum[c]) - __logf(nomsum[c]);
#pragma unroll
    for (int off = 32; off >= 1; off >>= 1)
        local += __shfl_down(local, off);
    __shared__ float red[4];
    const int wid = tid >> 6, lane = tid & 63;
    if (lane == 0) red[wid] = local;
    __syncthreads();
    if (tid == 0) {
        const float v2t = (red[0] + red[1]) + (red[2] + red[3]);
        // mean(log rowsum - s) + mean(log colsum - log nomsum)
        out[0] = (acc[0] - acc[1]) * (1.0f / QN) + v2t * (1.0f / VN);
    }
}

extern "C" void kernel_launch(void* const* d_in, const int* in_sizes, int n_in,
                              void* d_out, int out_size, void* d_ws, size_t ws_size,
                              hipStream_t stream) {
    const float* scores = (const float*)d_in[0];
    const int*   labels = (const int*)d_in[1];
    float* ws  = (float*)d_ws;
    float* out = (float*)d_out;

    init_pass<<<(QN + VN + VN + 8 + 255) / 256, 256, 0, stream>>>(ws);
    gather_pass<<<QN / 256, 256, 0, stream>>>(scores, labels, ws);
    main_pass<<<NB, TB, 0, stream>>>(scores, ws);
    reduce_pass<<<192, 256, 0, stream>>>(ws);
    final_pass<<<1, 256, 0, stream>>>(ws, out);
}